// Round 5
// baseline (213.650 us; speedup 1.0000x reference)
//
#include <hip/hip_runtime.h>

typedef __bf16 bf16x8 __attribute__((ext_vector_type(8)));
typedef float f32x4 __attribute__((ext_vector_type(4)));
typedef float fl4 __attribute__((ext_vector_type(4)));
typedef unsigned short us4 __attribute__((ext_vector_type(4)));
typedef unsigned short us8 __attribute__((ext_vector_type(8)));

__device__ __forceinline__ unsigned short f2bf(float f) {
  unsigned u = __builtin_bit_cast(unsigned, f);
  u += 0x7fffu + ((u >> 16) & 1u);
  return (unsigned short)(u >> 16);
}
__device__ __forceinline__ float bf2f(unsigned short h) {
  unsigned u = ((unsigned)h) << 16;
  return __builtin_bit_cast(float, u);
}

__device__ __forceinline__ void async16(const void* g, void* l) {
  __builtin_amdgcn_global_load_lds(
      (const __attribute__((address_space(1))) unsigned int*)g,
      (__attribute__((address_space(3))) unsigned int*)l, 16, 0, 0);
}

#define BARM() asm volatile("s_barrier" ::: "memory")
#define VMCNT4() asm volatile("s_waitcnt vmcnt(4)" ::: "memory")
#define LGKM0() asm volatile("s_waitcnt lgkmcnt(0)" ::: "memory")

// ---------------- fp32 -> bf16 convert (x and W merged) ----------------
__global__ __launch_bounds__(256) void cvt_bf16_2(const float* __restrict__ sA,
                                                  unsigned short* __restrict__ dA, int nA,
                                                  const float* __restrict__ sB,
                                                  unsigned short* __restrict__ dB, int nB) {
  int i = blockIdx.x * 256 + threadIdx.x;
  const float* s;
  unsigned short* d;
  if (i < nA) {
    s = sA; d = dA;
  } else {
    i -= nA;
    if (i >= nB) return;
    s = sB; d = dB;
  }
  fl4 f = ((const fl4*)s)[i];
  us4 o;
  o[0] = f2bf(f[0]); o[1] = f2bf(f[1]); o[2] = f2bf(f[2]); o[3] = f2bf(f[3]);
  ((us4*)d)[i] = o;
}

// ---------------- transpose v: vT[b][c][t] = kqv[b*2048+t][2048+c] ----------------
__global__ __launch_bounds__(256) void transpose_v(const unsigned short* __restrict__ kqv,
                                                   unsigned short* __restrict__ vT) {
  int b = blockIdx.z;
  int t0 = blockIdx.x * 64;
  int c0 = blockIdx.y * 64;
  __shared__ unsigned short tile[64][68];
  int tid = threadIdx.x;
#pragma unroll
  for (int i = 0; i < 4; ++i) {
    int idx = i * 256 + tid;
    int r = idx >> 4;
    int c4 = (idx & 15) * 4;
    const unsigned short* src = kqv + ((size_t)(b * 2048 + t0 + r)) * 3072 + 2048 + c0 + c4;
    us4 v = *(const us4*)src;
    *(us4*)&tile[r][c4] = v;
  }
  __syncthreads();
#pragma unroll
  for (int i = 0; i < 4; ++i) {
    int idx = i * 256 + tid;
    int rc = idx >> 4;
    int t4 = (idx & 15) * 4;
    us4 v;
    v[0] = tile[t4 + 0][rc]; v[1] = tile[t4 + 1][rc];
    v[2] = tile[t4 + 2][rc]; v[3] = tile[t4 + 3][rc];
    unsigned short* dst = vT + ((size_t)(b * 1024 + c0 + rc)) * 2048 + t0 + t4;
    *(us4*)dst = v;
  }
}

// ---------------- 256x256 8-phase bf16 MFMA GEMM (g0 only; r4 verbatim) -------
template <int EPI>
__global__ __launch_bounds__(512, 2) void gemm8p(
    const unsigned short* __restrict__ A, int lda, long long sA,
    const unsigned short* __restrict__ B, int ldb, long long sB,
    void* __restrict__ Cv, int ldc, long long sC,
    const float* __restrict__ bias, float scale, int K, int NBX) {
  int bx, by;
  const int bz = blockIdx.z;
  if (EPI == 0) {
    int flat = blockIdx.x;
    int q = (int)gridDim.x >> 3;
    int swz = (flat & 7) * q + (flat >> 3);
    bx = swz % NBX; by = swz / NBX;
  } else {
    bx = blockIdx.x; by = blockIdx.y;
    if (EPI == 1 && bx > by) return;
  }
  A += (size_t)bz * sA;
  B += (size_t)bz * sB;
  const int rowBase = by * 256;
  const int colBase = bx * 256;
  const int nk = (EPI == 2) ? (rowBase + 256) / 64 : K / 64;

  __shared__ __align__(16) unsigned char lds[131072];
  const int tid = threadIdx.x;
  const int lane = tid & 63;
  const int wid = tid >> 6;
  const int wr = wid >> 2;
  const int wc = wid & 3;
  const int l15 = lane & 15, l4 = lane >> 4, l7 = lane & 7;

  f32x4 acc[8][4] = {};
  bf16x8 af0[4], af1[4], bf0[4], bf1[4];

  const unsigned short* Ab = A + (size_t)rowBase * lda;
  const unsigned short* Bb = B + (size_t)colBase * ldb;
  unsigned loff[2][2];
  unsigned lldso[2];
#pragma unroll
  for (int i = 0; i < 2; ++i) {
    int off = (i * 512 + tid) * 16;
    int r = off >> 7;
    int sb = ((off >> 4) & 7) ^ (r & 7);
    lldso[i] = (unsigned)off;
#pragma unroll
    for (int h = 0; h < 2; ++h)
      loff[h][i] = (unsigned)((h * 128 + r) * lda + sb * 8);
  }

  auto STAGE = [&](int bufc, int isB, int half, const unsigned short* Gb, int koff) {
#pragma unroll
    for (int i = 0; i < 2; ++i)
      async16(Gb + (size_t)(loff[half][i] + (unsigned)koff),
              lds + bufc * 65536 + isB * 32768 + half * 16384 + lldso[i]);
  };
  auto RDA = [&](int bufc, int m, int kk) -> bf16x8 {
    int row = m * 16 + l15;
    int blk = (kk * 4 + l4) ^ l7;
    return *(const bf16x8*)(lds + bufc * 65536 + wr * 16384 + row * 128 + blk * 16);
  };
  auto RDB = [&](int bufc, int n, int kk) -> bf16x8 {
    int row = (wc & 1) * 64 + n * 16 + l15;
    int blk = (kk * 4 + l4) ^ l7;
    return *(const bf16x8*)(lds + bufc * 65536 + 32768 + (wc >> 1) * 16384 +
                            row * 128 + blk * 16);
  };

#define RDAF(dst, BUF, MB, KK)                                                 \
  _Pragma("unroll") for (int mi = 0; mi < 4; ++mi) dst[mi] = RDA((BUF), (MB) + mi, (KK))
#define RDBF2(dst, BUF, N0, KK)                                                \
  do { dst[N0] = RDB((BUF), (N0), (KK)); dst[(N0) + 1] = RDB((BUF), (N0) + 1, (KK)); } while (0)
#define RDBF4(dst, BUF, KK)                                                    \
  _Pragma("unroll") for (int n = 0; n < 4; ++n) dst[n] = RDB((BUF), n, (KK))

#define PH(MB, AFU, BFU, STG, GATE, RDS)                                       \
  do {                                                                         \
    STG;                                                                       \
    BARM();                                                                    \
    GATE;                                                                      \
    RDS;                                                                       \
    __builtin_amdgcn_s_setprio(1);                                             \
    _Pragma("unroll") for (int mi = 0; mi < 4; ++mi)                           \
    _Pragma("unroll") for (int n = 0; n < 4; ++n)                              \
        acc[(MB) + mi][n] = __builtin_amdgcn_mfma_f32_16x16x32_bf16(           \
            AFU[mi], BFU[n], acc[(MB) + mi][n], 0, 0, 0);                      \
    __builtin_amdgcn_s_setprio(0);                                             \
    LGKM0();                                                                   \
    BARM();                                                                    \
  } while (0)

  STAGE(0, 0, 0, Ab, 0);
  STAGE(0, 0, 1, Ab, 0);
  STAGE(0, 1, 0, Bb, 0);
  STAGE(0, 1, 1, Bb, 0);
  {
    int k1 = ((1 < nk - 1) ? 1 : (nk - 1)) * 64;
    STAGE(1, 1, 0, Bb, k1);
    STAGE(1, 1, 1, Bb, k1);
  }
  VMCNT4();
  BARM();
  RDAF(af0, 0, 0, 0);
  RDBF4(bf0, 0, 0);
  const int nt2 = nk >> 1;
  for (int it = 0; it < nt2; ++it) {
    int t = it * 2;
    int tA1 = t + 1 < nk - 1 ? t + 1 : nk - 1;
    int t2 = t + 2 < nk - 1 ? t + 2 : nk - 1;
    int t3 = t + 3 < nk - 1 ? t + 3 : nk - 1;
    int kA1 = tA1 * 64, k2 = t2 * 64, k3 = t3 * 64;
    PH(0, af0, bf0, STAGE(1, 0, 0, Ab, kA1), (void)0,
       { RDAF(af1, 0, 4, 0); RDBF2(bf1, 0, 0, 1); });
    PH(4, af1, bf0, STAGE(1, 0, 1, Ab, kA1), (void)0,
       { RDAF(af0, 0, 0, 1); RDBF2(bf1, 0, 2, 1); });
    PH(0, af0, bf1, STAGE(0, 1, 0, Bb, k2), (void)0,
       { RDAF(af1, 0, 4, 1); });
    PH(4, af1, bf1, STAGE(0, 1, 1, Bb, k2), VMCNT4(),
       { RDAF(af0, 1, 0, 0); RDBF4(bf0, 1, 0); });
    PH(0, af0, bf0, STAGE(0, 0, 0, Ab, k2), (void)0,
       { RDAF(af1, 1, 4, 0); RDBF2(bf1, 1, 0, 1); });
    PH(4, af1, bf0, STAGE(0, 0, 1, Ab, k2), (void)0,
       { RDAF(af0, 1, 0, 1); RDBF2(bf1, 1, 2, 1); });
    PH(0, af0, bf1, STAGE(1, 1, 0, Bb, k3), (void)0,
       { RDAF(af1, 1, 4, 1); });
    PH(4, af1, bf1, STAGE(1, 1, 1, Bb, k3), VMCNT4(),
       { RDAF(af0, 0, 0, 0); RDBF4(bf0, 0, 0); });
  }
#undef PH
#undef RDAF
#undef RDBF2
#undef RDBF4

  const int cr = l4 * 4;
  if constexpr (EPI == 0) {
    unsigned short* C = (unsigned short*)Cv;
#pragma unroll
    for (int n = 0; n < 4; ++n) {
      int col = colBase + wc * 64 + n * 16 + l15;
      float bv = bias[col];
#pragma unroll
      for (int m = 0; m < 8; ++m) {
        int row = rowBase + wr * 128 + m * 16 + cr;
#pragma unroll
        for (int i = 0; i < 4; ++i)
          C[(size_t)(row + i) * ldc + col] = f2bf(acc[m][n][i] + bv);
      }
    }
  } else if constexpr (EPI == 1) {
    unsigned short* C = (unsigned short*)Cv + (size_t)bz * sC;
#pragma unroll
    for (int n = 0; n < 4; ++n) {
      int col = colBase + wc * 64 + n * 16 + l15;
#pragma unroll
      for (int m = 0; m < 8; ++m) {
        int row = rowBase + wr * 128 + m * 16 + cr;
#pragma unroll
        for (int i = 0; i < 4; ++i)
          C[(size_t)(row + i) * ldc + col] = f2bf(acc[m][n][i] * scale);
      }
    }
  } else {
    float* C = (float*)Cv + (size_t)bz * sC;
#pragma unroll
    for (int n = 0; n < 4; ++n) {
      int col = colBase + wc * 64 + n * 16 + l15;
#pragma unroll
      for (int m = 0; m < 8; ++m) {
        int row = rowBase + wr * 128 + m * 16 + cr;
#pragma unroll
        for (int i = 0; i < 4; ++i)
          C[(size_t)(row + i) * ldc + col] = acc[m][n][i];
      }
    }
  }
}

// ---------------- 128x128 BK=32 gemm (round-1 engine) for g1/g2 ---------------
// EPI 1: bf16 out * scale, skip blocks above diagonal.
// EPI 2: f32 out, K truncated at diagonal, heavy blocks dispatched first (by flip).
#define BK 32

template <int EPI>
__global__ __launch_bounds__(256) void gemm_bt(
    const unsigned short* __restrict__ A, int lda, long long sA,
    const unsigned short* __restrict__ B, int ldb, long long sB,
    void* __restrict__ Cv, int ldc, long long sC,
    float scale, int K) {
  int bx = blockIdx.x, by = blockIdx.y, bz = blockIdx.z;
  if (EPI == 2) by = (int)gridDim.y - 1 - by;  // heavy diagonal blocks first
  if (EPI == 1 && bx > by) return;             // fully-masked causal block
  A += (size_t)bz * sA;
  B += (size_t)bz * sB;
  const int rowBase = by * 128;
  const int colBase = bx * 128;
  const int nk = (EPI == 2) ? (rowBase + 128) / BK : K / BK;

  __shared__ __align__(16) unsigned char lds[16384];  // A tile 8KB | B tile 8KB
  const int tid = threadIdx.x;
  const int lane = tid & 63;
  const int wid = tid >> 6;
  const int wr = (wid >> 1) * 64;
  const int wc = (wid & 1) * 64;

  f32x4 acc[4][4] = {};

  for (int kt = 0; kt < nk; ++kt) {
    __syncthreads();
    const int kof = kt * BK;
#pragma unroll
    for (int i = 0; i < 2; ++i) {
      int off = (i * 256 + tid) * 16;
      int r = off >> 6;
      int gblk = ((off >> 4) & 3) ^ ((r >> 1) & 3);
      async16(A + (size_t)(rowBase + r) * lda + kof + gblk * 8, lds + off);
      async16(B + (size_t)(colBase + r) * ldb + kof + gblk * 8, lds + 8192 + off);
    }
    __syncthreads();

    bf16x8 af[4], bfr[4];
#pragma unroll
    for (int m = 0; m < 4; ++m) {
      int row = wr + m * 16 + (lane & 15);
      int addr = row * 64 + ((((lane >> 4) ^ (row >> 1)) & 3) * 16);
      af[m] = *(const bf16x8*)(lds + addr);
    }
#pragma unroll
    for (int n = 0; n < 4; ++n) {
      int row = wc + n * 16 + (lane & 15);
      int addr = row * 64 + ((((lane >> 4) ^ (row >> 1)) & 3) * 16);
      bfr[n] = *(const bf16x8*)(lds + 8192 + addr);
    }
#pragma unroll
    for (int m = 0; m < 4; ++m)
#pragma unroll
      for (int n = 0; n < 4; ++n)
        acc[m][n] = __builtin_amdgcn_mfma_f32_16x16x32_bf16(af[m], bfr[n], acc[m][n], 0, 0, 0);
  }

  const int cr = (lane >> 4) * 4;
  const int cc = lane & 15;
  if constexpr (EPI == 1) {
    unsigned short* C = (unsigned short*)Cv + (size_t)bz * sC;
#pragma unroll
    for (int n = 0; n < 4; ++n) {
      int col = colBase + wc + n * 16 + cc;
#pragma unroll
      for (int m = 0; m < 4; ++m) {
        int row = rowBase + wr + m * 16 + cr;
#pragma unroll
        for (int i = 0; i < 4; ++i)
          C[(size_t)(row + i) * ldc + col] = f2bf(acc[m][n][i] * scale);
      }
    }
  } else {
    float* C = (float*)Cv + (size_t)bz * sC;
#pragma unroll
    for (int n = 0; n < 4; ++n) {
      int col = colBase + wc + n * 16 + cc;
#pragma unroll
      for (int m = 0; m < 4; ++m) {
        int row = rowBase + wr + m * 16 + cr;
#pragma unroll
        for (int i = 0; i < 4; ++i)
          C[(size_t)(row + i) * ldc + col] = acc[m][n][i];
      }
    }
  }
}

// ---------------- causal softmax over S rows (in place, bf16) ----------------
// Prefix-trimmed: loads only cols < nv; stores only cols < bound where
// bound = (t/128+1)*128 (the K-range g2's 128-tile K-truncation reads).
__global__ __launch_bounds__(256) void softmax_causal(unsigned short* __restrict__ S) {
  const int T = 2048;
  int t = blockIdx.x, b = blockIdx.y;
  unsigned short* row = S + ((size_t)b * T + t) * T;
  const int nv = t + 1;
  const int bound = ((t >> 7) + 1) << 7;
  int tid = threadIdx.x;
  int lane = tid & 63, wid = tid >> 6;
  int s0 = tid * 8;
  us8 raw = {};
  if (s0 < nv) raw = *(const us8*)(row + s0);
  float v[8];
  float m = -3.0e38f;
#pragma unroll
  for (int j = 0; j < 8; ++j) {
    v[j] = bf2f(raw[j]);
    if (s0 + j < nv) m = fmaxf(m, v[j]);
  }
#pragma unroll
  for (int o = 32; o > 0; o >>= 1) m = fmaxf(m, __shfl_xor(m, o, 64));
  __shared__ float red[4];
  if (lane == 0) red[wid] = m;
  __syncthreads();
  m = fmaxf(fmaxf(red[0], red[1]), fmaxf(red[2], red[3]));
  __syncthreads();
  float sum = 0.f;
#pragma unroll
  for (int j = 0; j < 8; ++j) {
    float e = (s0 + j < nv) ? exp2f(v[j] - m) : 0.f;
    v[j] = e;
    sum += e;
  }
#pragma unroll
  for (int o = 32; o > 0; o >>= 1) sum += __shfl_xor(sum, o, 64);
  if (lane == 0) red[wid] = sum;
  __syncthreads();
  sum = red[0] + red[1] + red[2] + red[3];
  float inv = 1.0f / sum;
  if (s0 < bound) {
    us8 outv;
#pragma unroll
    for (int j = 0; j < 8; ++j) outv[j] = f2bf(v[j] * inv);
    *(us8*)(row + s0) = outv;
  }
}

extern "C" void kernel_launch(void* const* d_in, const int* in_sizes, int n_in,
                              void* d_out, int out_size, void* d_ws, size_t ws_size,
                              hipStream_t stream) {
  const float* x = (const float*)d_in[0];      // [4,2048,1024]
  const float* W = (const float*)d_in[1];      // [3072,1024]
  const float* bias = (const float*)d_in[2];   // [3072]
  float* out = (float*)d_out;                  // [4,2048,1024]

  char* ws = (char*)d_ws;
  // layout: xbf 16MB (aliased by vT after gemm0) | wbf 6MB | kqv 48MB | S 32MB
  if (ws_size < 106954752u) return;
  unsigned short* xbf = (unsigned short*)(ws);
  unsigned short* vT = xbf;  // alias: xbf dead after gemm8p<0>
  unsigned short* wbf = (unsigned short*)(ws + 16777216);
  unsigned short* kqv = (unsigned short*)(ws + 23068672);
  unsigned short* S = (unsigned short*)(ws + 73400320);

  const float kSoftmaxScale = 1.4426950408889634f / 32.0f;  // log2(e)/sqrt(1024)

  cvt_bf16_2<<<11264, 256, 0, stream>>>(x, xbf, 2097152, W, wbf, 786432);

  // kqv = x @ W^T + b   (M=8192, N=3072, K=1024) ; grid 32x12 = 384, XCD swizzle
  gemm8p<0><<<dim3(384, 1, 1), 512, 0, stream>>>(
      xbf, 1024, 0LL, wbf, 1024, 0LL, kqv, 3072, 0LL, bias, 1.0f, 1024, 12);

  transpose_v<<<dim3(32, 16, 4), 256, 0, stream>>>(kqv, vT);

  // S = (k @ q^T) * log2e/32 (bf16), 128^2 tiles, causal blocks skipped
  gemm_bt<1><<<dim3(16, 16, 4), 256, 0, stream>>>(
      kqv, 3072, 2048LL * 3072, kqv + 1024, 3072, 2048LL * 3072,
      S, 2048, 2048LL * 2048, kSoftmaxScale, 1024);

  softmax_causal<<<dim3(2048, 4), 256, 0, stream>>>(S);

  // out = P @ vT^T (fp32), 128^2 tiles, K truncated at diagonal, heavy-first
  gemm_bt<2><<<dim3(8, 16, 4), 256, 0, stream>>>(
      S, 2048, 2048LL * 2048, vT, 2048, 1024LL * 2048,
      out, 1024, 2048LL * 1024, 1.0f, 2048);
}

// Round 6
// 189.567 us; speedup vs baseline: 1.1270x; 1.1270x over previous
//
#include <hip/hip_runtime.h>

typedef __bf16 bf16x8 __attribute__((ext_vector_type(8)));
typedef float f32x4 __attribute__((ext_vector_type(4)));
typedef float fl4 __attribute__((ext_vector_type(4)));
typedef unsigned short us4 __attribute__((ext_vector_type(4)));
typedef unsigned short us8 __attribute__((ext_vector_type(8)));

__device__ __forceinline__ unsigned short f2bf(float f) {
  unsigned u = __builtin_bit_cast(unsigned, f);
  u += 0x7fffu + ((u >> 16) & 1u);
  return (unsigned short)(u >> 16);
}
__device__ __forceinline__ float bf2f(unsigned short h) {
  unsigned u = ((unsigned)h) << 16;
  return __builtin_bit_cast(float, u);
}

__device__ __forceinline__ void async16(const void* g, void* l) {
  __builtin_amdgcn_global_load_lds(
      (const __attribute__((address_space(1))) unsigned int*)g,
      (__attribute__((address_space(3))) unsigned int*)l, 16, 0, 0);
}

#define BARM() asm volatile("s_barrier" ::: "memory")
#define VMCNT4() asm volatile("s_waitcnt vmcnt(4)" ::: "memory")
#define LGKM0() asm volatile("s_waitcnt lgkmcnt(0)" ::: "memory")
#define LGKM8() asm volatile("s_waitcnt lgkmcnt(8)" ::: "memory")
#define SCHEDB() __builtin_amdgcn_sched_barrier(0)

// ---------------- fp32 -> bf16 convert (x and W merged) ----------------
__global__ __launch_bounds__(256) void cvt_bf16_2(const float* __restrict__ sA,
                                                  unsigned short* __restrict__ dA, int nA,
                                                  const float* __restrict__ sB,
                                                  unsigned short* __restrict__ dB, int nB) {
  int i = blockIdx.x * 256 + threadIdx.x;
  const float* s;
  unsigned short* d;
  if (i < nA) {
    s = sA; d = dA;
  } else {
    i -= nA;
    if (i >= nB) return;
    s = sB; d = dB;
  }
  fl4 f = ((const fl4*)s)[i];
  us4 o;
  o[0] = f2bf(f[0]); o[1] = f2bf(f[1]); o[2] = f2bf(f[2]); o[3] = f2bf(f[3]);
  ((us4*)d)[i] = o;
}

// ---------------- transpose v: vT[b][c][t] = kqv[b*2048+t][2048+c] ----------------
__global__ __launch_bounds__(256) void transpose_v(const unsigned short* __restrict__ kqv,
                                                   unsigned short* __restrict__ vT) {
  int b = blockIdx.z;
  int t0 = blockIdx.x * 64;
  int c0 = blockIdx.y * 64;
  __shared__ unsigned short tile[64][68];
  int tid = threadIdx.x;
#pragma unroll
  for (int i = 0; i < 4; ++i) {
    int idx = i * 256 + tid;
    int r = idx >> 4;
    int c4 = (idx & 15) * 4;
    const unsigned short* src = kqv + ((size_t)(b * 2048 + t0 + r)) * 3072 + 2048 + c0 + c4;
    us4 v = *(const us4*)src;
    *(us4*)&tile[r][c4] = v;
  }
  __syncthreads();
#pragma unroll
  for (int i = 0; i < 4; ++i) {
    int idx = i * 256 + tid;
    int rc = idx >> 4;
    int t4 = (idx & 15) * 4;
    us4 v;
    v[0] = tile[t4 + 0][rc]; v[1] = tile[t4 + 1][rc];
    v[2] = tile[t4 + 2][rc]; v[3] = tile[t4 + 3][rc];
    unsigned short* dst = vT + ((size_t)(b * 1024 + c0 + rc)) * 2048 + t0 + t4;
    *(us4*)dst = v;
  }
}

// ---------------- 256x256 8-phase bf16 MFMA GEMM, m201-style schedule ---------
// 8 waves (2M x 4N), BK=64, LDS 128KB: 2 bufs x (A 32KB | B 32KB).
// Per K-tile, 4 phases (snake quadrants): reads in-phase BEFORE barrier,
// lgkmcnt(0)+sched_barrier after, then 16 MFMA. Staging 1 half-tile/phase:
//   ph1: rd A-q0+B01 (12), stage t+1.Ah0->buf1 ; ph2: rd B23 (4), t+1.Ah1
//   ph3: rd A-q1 (8), t+2.Bh0->buf0 (B dead after ph2) ; ph4: rd 0, t+2.Bh1, GATE
//   ph5-8: same on buf1, staging t+2.A->buf0 (A dead ph3) and t+3.B->buf1, GATE
// Gates vmcnt(4) at ph4/ph8 (leave 2 newest stages in flight; never 0).
template <int EPI>
__global__ __launch_bounds__(512, 2) void gemm8p(
    const unsigned short* __restrict__ A, int lda, long long sA,
    const unsigned short* __restrict__ B, int ldb, long long sB,
    void* __restrict__ Cv, int ldc, long long sC,
    const float* __restrict__ bias, float scale, int K, int NBX) {
  int bx, by;
  const int bz = blockIdx.z;
  if (EPI == 0) {
    int flat = blockIdx.x;
    int q = (int)gridDim.x >> 3;
    int swz = (flat & 7) * q + (flat >> 3);
    bx = swz % NBX; by = swz / NBX;
  } else {
    bx = blockIdx.x; by = blockIdx.y;
    if (EPI == 1 && bx > by) return;
  }
  A += (size_t)bz * sA;
  B += (size_t)bz * sB;
  const int rowBase = by * 256;
  const int colBase = bx * 256;
  const int nk = (EPI == 2) ? (rowBase + 256) / 64 : K / 64;

  __shared__ __align__(16) unsigned char lds[131072];
  const int tid = threadIdx.x;
  const int lane = tid & 63;
  const int wid = tid >> 6;
  const int wr = wid >> 2;
  const int wc = wid & 3;
  const int l15 = lane & 15, l4 = lane >> 4, l7 = lane & 7;

  f32x4 acc[8][4] = {};
  bf16x8 af0[4][2], af1[4][2], bf0[2][2], bf1[2][2];

  const unsigned short* Ab = A + (size_t)rowBase * lda;
  const unsigned short* Bb = B + (size_t)colBase * ldb;
  unsigned loff[2][2];
  unsigned lldso[2];
#pragma unroll
  for (int i = 0; i < 2; ++i) {
    int off = (i * 512 + tid) * 16;
    int r = off >> 7;
    int sb = ((off >> 4) & 7) ^ (r & 7);
    lldso[i] = (unsigned)off;
#pragma unroll
    for (int h = 0; h < 2; ++h)
      loff[h][i] = (unsigned)((h * 128 + r) * lda + sb * 8);
  }

  auto STAGE = [&](int bufc, int isB, int half, const unsigned short* Gb, int koff) {
#pragma unroll
    for (int i = 0; i < 2; ++i)
      async16(Gb + (size_t)(loff[half][i] + (unsigned)koff),
              lds + bufc * 65536 + isB * 32768 + half * 16384 + lldso[i]);
  };
  auto RDA = [&](int bufc, int m, int kk) -> bf16x8 {
    int row = m * 16 + l15;
    int blk = (kk * 4 + l4) ^ l7;
    return *(const bf16x8*)(lds + bufc * 65536 + wr * 16384 + row * 128 + blk * 16);
  };
  auto RDB = [&](int bufc, int n, int kk) -> bf16x8 {
    int row = (wc & 1) * 64 + n * 16 + l15;
    int blk = (kk * 4 + l4) ^ l7;
    return *(const bf16x8*)(lds + bufc * 65536 + 32768 + (wc >> 1) * 16384 +
                            row * 128 + blk * 16);
  };

// A quarter (8 reads): dst[mi][kk] ; B pair (4 reads): dst[nj][kk]
#define RDA8(dst, BUF, Q)                                                      \
  _Pragma("unroll") for (int mi = 0; mi < 4; ++mi)                             \
  _Pragma("unroll") for (int kk = 0; kk < 2; ++kk)                             \
      dst[mi][kk] = RDA((BUF), (Q) * 4 + mi, kk)
#define RDB4(dst, BUF, NB)                                                     \
  _Pragma("unroll") for (int nj = 0; nj < 2; ++nj)                             \
  _Pragma("unroll") for (int kk = 0; kk < 2; ++kk)                             \
      dst[nj][kk] = RDB((BUF), (NB) + nj, kk)

#define MFMAQ(MB, NB, AF, BF)                                                  \
  _Pragma("unroll") for (int kk = 0; kk < 2; ++kk)                             \
  _Pragma("unroll") for (int mi = 0; mi < 4; ++mi)                             \
  _Pragma("unroll") for (int nj = 0; nj < 2; ++nj)                             \
      acc[(MB) + mi][(NB) + nj] = __builtin_amdgcn_mfma_f32_16x16x32_bf16(     \
          AF[mi][kk], BF[nj][kk], acc[(MB) + mi][(NB) + nj], 0, 0, 0)

// phase: [reads][stage][hint][bar][lgkm0+schedbar][prio1][16 MFMA][prio0][gate][bar]
#define PH(RDS, STG, HINT, GATE, MB, NB, AF, BF)                               \
  do {                                                                         \
    RDS;                                                                       \
    STG;                                                                       \
    HINT;                                                                      \
    BARM();                                                                    \
    LGKM0();                                                                   \
    SCHEDB();                                                                  \
    __builtin_amdgcn_s_setprio(1);                                             \
    MFMAQ(MB, NB, AF, BF);                                                     \
    __builtin_amdgcn_s_setprio(0);                                             \
    GATE;                                                                      \
    BARM();                                                                    \
  } while (0)

  // prologue: tile0 (A,B)->buf0, tile1 B->buf1; gate leaves tile1.B in flight
  STAGE(0, 0, 0, Ab, 0);
  STAGE(0, 0, 1, Ab, 0);
  STAGE(0, 1, 0, Bb, 0);
  STAGE(0, 1, 1, Bb, 0);
  STAGE(1, 1, 0, Bb, 64);
  STAGE(1, 1, 1, Bb, 64);
  VMCNT4();
  BARM();

  const int nt2 = nk >> 1;
  for (int it = 0; it < nt2; ++it) {
    int t = it * 2;
    int kA1 = (t + 1) * 64;                            // t+1 <= nk-1 always
    int k2 = (t + 2 < nk - 1 ? t + 2 : nk - 1) * 64;   // clamp in final iter
    int k3 = (t + 3 < nk - 1 ? t + 3 : nk - 1) * 64;
    // tile t from buf0
    PH({ RDA8(af0, 0, 0); RDB4(bf0, 0, 0); }, STAGE(1, 0, 0, Ab, kA1), LGKM8(),
       (void)0, 0, 0, af0, bf0);
    PH({ RDB4(bf1, 0, 2); }, STAGE(1, 0, 1, Ab, kA1), (void)0,
       (void)0, 0, 2, af0, bf1);
    PH({ RDA8(af1, 0, 1); }, STAGE(0, 1, 0, Bb, k2), (void)0,
       (void)0, 4, 2, af1, bf1);
    PH({}, STAGE(0, 1, 1, Bb, k2), (void)0,
       VMCNT4(), 4, 0, af1, bf0);
    // tile t+1 from buf1
    PH({ RDA8(af0, 1, 0); RDB4(bf0, 1, 0); }, STAGE(0, 0, 0, Ab, k2), LGKM8(),
       (void)0, 0, 0, af0, bf0);
    PH({ RDB4(bf1, 1, 2); }, STAGE(0, 0, 1, Ab, k2), (void)0,
       (void)0, 0, 2, af0, bf1);
    PH({ RDA8(af1, 1, 1); }, STAGE(1, 1, 0, Bb, k3), (void)0,
       (void)0, 4, 2, af1, bf1);
    PH({}, STAGE(1, 1, 1, Bb, k3), (void)0,
       VMCNT4(), 4, 0, af1, bf0);
  }
#undef PH
#undef MFMAQ
#undef RDA8
#undef RDB4

  const int cr = l4 * 4;
  if constexpr (EPI == 0) {
    unsigned short* C = (unsigned short*)Cv;
#pragma unroll
    for (int n = 0; n < 4; ++n) {
      int col = colBase + wc * 64 + n * 16 + l15;
      float bv = bias[col];
#pragma unroll
      for (int m = 0; m < 8; ++m) {
        int row = rowBase + wr * 128 + m * 16 + cr;
#pragma unroll
        for (int i = 0; i < 4; ++i)
          C[(size_t)(row + i) * ldc + col] = f2bf(acc[m][n][i] + bv);
      }
    }
  } else if constexpr (EPI == 1) {
    unsigned short* C = (unsigned short*)Cv + (size_t)bz * sC;
#pragma unroll
    for (int n = 0; n < 4; ++n) {
      int col = colBase + wc * 64 + n * 16 + l15;
#pragma unroll
      for (int m = 0; m < 8; ++m) {
        int row = rowBase + wr * 128 + m * 16 + cr;
#pragma unroll
        for (int i = 0; i < 4; ++i)
          C[(size_t)(row + i) * ldc + col] = f2bf(acc[m][n][i] * scale);
      }
    }
  } else {
    float* C = (float*)Cv + (size_t)bz * sC;
#pragma unroll
    for (int n = 0; n < 4; ++n) {
      int col = colBase + wc * 64 + n * 16 + l15;
#pragma unroll
      for (int m = 0; m < 8; ++m) {
        int row = rowBase + wr * 128 + m * 16 + cr;
#pragma unroll
        for (int i = 0; i < 4; ++i)
          C[(size_t)(row + i) * ldc + col] = acc[m][n][i];
      }
    }
  }
}

// ---------------- causal softmax over S rows (in place, bf16) ----------------
// Prefix-trimmed: loads only cols < nv; stores only cols < bound where
// bound = (t/256+1)*256 (the K-range gemm8p<2>'s 256-tile K-truncation reads).
__global__ __launch_bounds__(256) void softmax_causal(unsigned short* __restrict__ S) {
  const int T = 2048;
  int t = blockIdx.x, b = blockIdx.y;
  unsigned short* row = S + ((size_t)b * T + t) * T;
  const int nv = t + 1;
  const int bound = ((t >> 8) + 1) << 8;
  int tid = threadIdx.x;
  int lane = tid & 63, wid = tid >> 6;
  int s0 = tid * 8;
  us8 raw = {};
  if (s0 < nv) raw = *(const us8*)(row + s0);
  float v[8];
  float m = -3.0e38f;
#pragma unroll
  for (int j = 0; j < 8; ++j) {
    v[j] = bf2f(raw[j]);
    if (s0 + j < nv) m = fmaxf(m, v[j]);
  }
#pragma unroll
  for (int o = 32; o > 0; o >>= 1) m = fmaxf(m, __shfl_xor(m, o, 64));
  __shared__ float red[4];
  if (lane == 0) red[wid] = m;
  __syncthreads();
  m = fmaxf(fmaxf(red[0], red[1]), fmaxf(red[2], red[3]));
  __syncthreads();
  float sum = 0.f;
#pragma unroll
  for (int j = 0; j < 8; ++j) {
    float e = (s0 + j < nv) ? exp2f(v[j] - m) : 0.f;
    v[j] = e;
    sum += e;
  }
#pragma unroll
  for (int o = 32; o > 0; o >>= 1) sum += __shfl_xor(sum, o, 64);
  if (lane == 0) red[wid] = sum;
  __syncthreads();
  sum = red[0] + red[1] + red[2] + red[3];
  float inv = 1.0f / sum;
  if (s0 < bound) {
    us8 outv;
#pragma unroll
    for (int j = 0; j < 8; ++j) outv[j] = f2bf(v[j] * inv);
    *(us8*)(row + s0) = outv;
  }
}

extern "C" void kernel_launch(void* const* d_in, const int* in_sizes, int n_in,
                              void* d_out, int out_size, void* d_ws, size_t ws_size,
                              hipStream_t stream) {
  const float* x = (const float*)d_in[0];      // [4,2048,1024]
  const float* W = (const float*)d_in[1];      // [3072,1024]
  const float* bias = (const float*)d_in[2];   // [3072]
  float* out = (float*)d_out;                  // [4,2048,1024]

  char* ws = (char*)d_ws;
  // layout: xbf 16MB (aliased by vT after gemm0) | wbf 6MB | kqv 48MB | S 32MB
  if (ws_size < 106954752u) return;
  unsigned short* xbf = (unsigned short*)(ws);
  unsigned short* vT = xbf;  // alias: xbf dead after gemm8p<0>
  unsigned short* wbf = (unsigned short*)(ws + 16777216);
  unsigned short* kqv = (unsigned short*)(ws + 23068672);
  unsigned short* S = (unsigned short*)(ws + 73400320);

  const float kSoftmaxScale = 1.4426950408889634f / 32.0f;  // log2(e)/sqrt(1024)

  cvt_bf16_2<<<11264, 256, 0, stream>>>(x, xbf, 2097152, W, wbf, 786432);

  // kqv = x @ W^T + b   (M=8192, N=3072, K=1024) ; grid 32x12 = 384, XCD swizzle
  gemm8p<0><<<dim3(384, 1, 1), 512, 0, stream>>>(
      xbf, 1024, 0LL, wbf, 1024, 0LL, kqv, 3072, 0LL, bias, 1.0f, 1024, 12);

  transpose_v<<<dim3(32, 16, 4), 256, 0, stream>>>(kqv, vT);

  // S = (k @ q^T) * log2e/32 (bf16), causal blocks skipped
  gemm8p<1><<<dim3(8, 8, 4), 512, 0, stream>>>(
      kqv, 3072, 2048LL * 3072, kqv + 1024, 3072, 2048LL * 3072,
      S, 2048, 2048LL * 2048, nullptr, kSoftmaxScale, 1024, 0);

  softmax_causal<<<dim3(2048, 4), 256, 0, stream>>>(S);

  // out = P @ vT^T (fp32), K truncated at diagonal
  gemm8p<2><<<dim3(4, 8, 4), 512, 0, stream>>>(
      S, 2048, 2048LL * 2048, vT, 2048, 1024LL * 2048,
      out, 1024, 2048LL * 1024, nullptr, 1.0f, 2048, 0);
}